// Round 9
// baseline (233.834 us; speedup 1.0000x reference)
//
#include <hip/hip_runtime.h>

#define C_IN   672
#define C_OUT  128
#define HW     49
#define XELEMS (C_IN*HW)      // 32928
#define BK     32             // K per step = one MFMA k-step
#define NK     21             // 672/32
#define CHUNK  (BK*HW)        // 1568

typedef short  short8 __attribute__((ext_vector_type(8)));
typedef float  f8v    __attribute__((ext_vector_type(8)));
typedef float  f4     __attribute__((ext_vector_type(4)));
typedef float  f2     __attribute__((ext_vector_type(2)));

typedef const __attribute__((address_space(1))) float*  gfp;
typedef const __attribute__((address_space(1))) f2*     gf2p;
typedef const __attribute__((address_space(1))) short8* gs8p;
typedef const __attribute__((address_space(1))) unsigned short* gusp;
typedef __attribute__((address_space(1))) float*        gwp;
typedef const __attribute__((address_space(3))) f4*     lf4p;

__device__ __forceinline__ void waitlgkm0() {
    asm volatile("s_waitcnt lgkmcnt(0)" ::: "memory");
}

__device__ __forceinline__ unsigned short f2bf(float f) {
    unsigned u = __float_as_uint(f);
    u += 0x7fffu + ((u >> 16) & 1u);
    return (unsigned short)(u >> 16);
}

__global__ __launch_bounds__(256) void prep_kernel(
        const float* __restrict__ gamma,
        const float* __restrict__ beta,
        const float* __restrict__ rmean,
        const float* __restrict__ rvar,
        const float* __restrict__ W,
        unsigned short* __restrict__ Wbf,
        float2* __restrict__ ss2) {
    int i = blockIdx.x * 256 + threadIdx.x;
    if (i < C_IN) {
        float inv = rsqrtf(rvar[i] + 1e-5f);
        float sc  = gamma[i] * inv;
        ss2[i] = make_float2(sc, beta[i] - rmean[i] * sc);
    }
    if (i < C_OUT * C_IN) Wbf[i] = f2bf(W[i]);
}

// out_b(128x49) = W(128x672) @ relu(x_b*scale+shift)(672x49), via OPERAND
// SWAP: D = A*B with A = h^T (M=s), B = W^T (N=o). R14 rationale: six
// schedules (R5,R7,R8,R10,R11,R12) all pinned gemm at ~75-85us while every
// static model (VALU ~10us/CU, per-CU BW share ~25us, Little's-law latency)
// says 25-40us. The ONE structural invariant of all six was the h staging
// path: LDS hT tile + per-element transposed scatter + per-step lgkmcnt(0)
// + write->read LDS dependency inside the step critical path. This version
// DELETES it: the A-fragment layout (lane row=l16=s, k=quad*8+j=c) is
// loadable straight from global x (8 dword loads, stride 196B, 4x64B lines
// per inst = same coalescing class as any dword stream), BN+ReLU+bf16 is
// applied in-register, and the frag feeds MFMA directly. B = W^T frag is a
// contiguous short8 of Wbf. C/D emerges row=s col=o -> s-contiguous dword
// stores to out. LDS holds only the 5.4KB (scale,shift) table (read as
// quad-uniform b128 broadcasts). No barriers in the loop, no hT, no
// scatter. x and W are E/O double-buffered in named ext-vector regs
// (constant indices only, R9 scratch lesson); 1-step issue->use lead;
// compiler inserts counted vmcnt per use (in-order queues, AS(1) loads
// never bump lgkmcnt). 2 waves per b (o-halves), 4 waves/block, 512 blocks.
__global__ __launch_bounds__(256, 2) void gemm_kernel(
        const float* __restrict__ x,
        const unsigned short* __restrict__ Wbf,
        const float2* __restrict__ ss2,
        float* __restrict__ out) {
    __shared__ f2 s_ss[C_IN];            // (scale,shift) interleaved, 5.4 KB

    const int tid  = threadIdx.x;
    const int wv   = tid >> 6;           // 0..3
    const int lane = tid & 63;
    const int quad = lane >> 4;
    const int l16  = lane & 15;
    const int b     = blockIdx.x * 2 + (wv >> 1);
    const int obase = (wv & 1) * 64;     // o-half of this wave

    gfp  xg = (gfp)x;
    gusp wg = (gusp)Wbf;
    gwp  og = (gwp)out;
    lf4p ssl4 = (lf4p)&s_ss[0];

    // stage ss table (f2, coalesced); only barrier in the kernel.
    for (int i = tid; i < C_IN; i += 256)
        s_ss[i] = ((gf2p)ss2)[i];
    waitlgkm0();
    __builtin_amdgcn_s_barrier();

    const gfp xbp = xg + (size_t)b * XELEMS;

    // ---- named SSA state (ext-vectors, constant-indexed only) ----
    f8v xE0, xE1, xE2, xE3, xO0, xO1, xO2, xO3;   // x raw: 4 s-tiles x 8 c
    short8 wE0, wE1, wE2, wE3, wO0, wO1, wO2, wO3; // W^T frags: 4 o-tiles
    f4 acc00={0,0,0,0}, acc01={0,0,0,0}, acc02={0,0,0,0}, acc03={0,0,0,0};
    f4 acc10={0,0,0,0}, acc11={0,0,0,0}, acc12={0,0,0,0}, acc13={0,0,0,0};
    f4 acc20={0,0,0,0}, acc21={0,0,0,0}, acc22={0,0,0,0}, acc23={0,0,0,0};
    f4 acc30={0,0,0,0}, acc31={0,0,0,0}, acc32={0,0,0,0}, acc33={0,0,0,0};

// 32 dword loads: tile t covers A rows s = t*16+l16 (tile 3 clamped to s=48;
// rows 49..63 feed only unstored D rows -- garbage OK). c = kc*32+quad*8+j.
#define ISSUE_X(S, kc) do {                                             \
    gfp _b = xbp + (size_t)(kc) * CHUNK + (size_t)quad * 8 * HW;        \
    _Pragma("unroll")                                                   \
    for (int j = 0; j < 8; ++j) {                                       \
        x##S##0[j] = _b[j * HW + l16];                                  \
        x##S##1[j] = _b[j * HW + 16 + l16];                             \
        x##S##2[j] = _b[j * HW + 32 + l16];                             \
        x##S##3[j] = _b[j * HW + 48];                                   \
    } } while (0)

// B = W^T frag: lane holds B[k=quad*8+j][n=l16], value = Wbf[o][c]:
// contiguous short8 at row o = obase + nt*16 + l16.
#define ISSUE_W(S, kc) do {                                             \
    gusp _w = wg + (size_t)(obase + l16) * C_IN + (kc) * BK + quad * 8; \
    w##S##0 = *(gs8p)(_w);                                              \
    w##S##1 = *(gs8p)(_w + 16 * C_IN);                                  \
    w##S##2 = *(gs8p)(_w + 32 * C_IN);                                  \
    w##S##3 = *(gs8p)(_w + 48 * C_IN);                                  \
} while (0)

#define BF1(xv, sc, sh) f2bf(fmaxf((xv) * (sc) + (sh), 0.f))
// build one A-frag from 8 raw x + 4 ss-f4s (each f4 = sc0,sh0,sc1,sh1)
#define MKA1(AF, XV, u0, u1, u2, u3) do {                               \
    AF[0] = (short)BF1(XV[0], u0[0], u0[1]);                            \
    AF[1] = (short)BF1(XV[1], u0[2], u0[3]);                            \
    AF[2] = (short)BF1(XV[2], u1[0], u1[1]);                            \
    AF[3] = (short)BF1(XV[3], u1[2], u1[3]);                            \
    AF[4] = (short)BF1(XV[4], u2[0], u2[1]);                            \
    AF[5] = (short)BF1(XV[5], u2[2], u2[3]);                            \
    AF[6] = (short)BF1(XV[6], u3[0], u3[1]);                            \
    AF[7] = (short)BF1(XV[7], u3[2], u3[3]);                            \
} while (0)

#define MM(ACC, AF, WF) ACC = __builtin_amdgcn_mfma_f32_16x16x32_bf16(AF, WF, ACC, 0, 0, 0)

// step K: issue K+1 (both streams) -> ss broadcast read -> in-reg transform
// (compiler: counted vmcnt on x(K), K+1 stays outstanding) -> 16 MFMAs.
#define STEP(K, C, N) do {                                              \
    if ((K) + 1 < NK) { ISSUE_X(N, (K) + 1); ISSUE_W(N, (K) + 1); }     \
    int _sb = (K) * 16 + quad * 4;                                      \
    f4 u0 = ssl4[_sb], u1 = ssl4[_sb + 1], u2 = ssl4[_sb + 2], u3 = ssl4[_sb + 3]; \
    short8 af0, af1, af2, af3;                                          \
    MKA1(af0, x##C##0, u0, u1, u2, u3);                                 \
    MKA1(af1, x##C##1, u0, u1, u2, u3);                                 \
    MKA1(af2, x##C##2, u0, u1, u2, u3);                                 \
    MKA1(af3, x##C##3, u0, u1, u2, u3);                                 \
    MM(acc00, af0, w##C##0); MM(acc01, af0, w##C##1);                   \
    MM(acc02, af0, w##C##2); MM(acc03, af0, w##C##3);                   \
    MM(acc10, af1, w##C##0); MM(acc11, af1, w##C##1);                   \
    MM(acc12, af1, w##C##2); MM(acc13, af1, w##C##3);                   \
    MM(acc20, af2, w##C##0); MM(acc21, af2, w##C##1);                   \
    MM(acc22, af2, w##C##2); MM(acc23, af2, w##C##3);                   \
    MM(acc30, af3, w##C##0); MM(acc31, af3, w##C##1);                   \
    MM(acc32, af3, w##C##2); MM(acc33, af3, w##C##3);                   \
} while (0)

    ISSUE_X(E, 0); ISSUE_W(E, 0);
    STEP(0,  E, O); STEP(1,  O, E); STEP(2,  E, O); STEP(3,  O, E);
    STEP(4,  E, O); STEP(5,  O, E); STEP(6,  E, O); STEP(7,  O, E);
    STEP(8,  E, O); STEP(9,  O, E); STEP(10, E, O); STEP(11, O, E);
    STEP(12, E, O); STEP(13, O, E); STEP(14, E, O); STEP(15, O, E);
    STEP(16, E, O); STEP(17, O, E); STEP(18, E, O); STEP(19, O, E);
    STEP(20, E, O);

    // epilogue: D row = s = st*16 + quad*4 + i (contiguous i), col = o.
    // st<3 fully valid; st=3 only s=48 (quad 0, reg 0).
    gwp ob = og + (size_t)b * (C_OUT * HW);
#define EPI(ST, NT, ACC) do {                                           \
    int _o = obase + (NT) * 16 + l16;                                   \
    if ((ST) < 3) {                                                     \
        gwp _p = ob + (size_t)_o * HW + (ST) * 16 + quad * 4;           \
        _p[0] = ACC[0]; _p[1] = ACC[1]; _p[2] = ACC[2]; _p[3] = ACC[3]; \
    } else if (quad == 0) {                                             \
        ob[(size_t)_o * HW + 48] = ACC[0];                              \
    } } while (0)
    EPI(0, 0, acc00); EPI(0, 1, acc01); EPI(0, 2, acc02); EPI(0, 3, acc03);
    EPI(1, 0, acc10); EPI(1, 1, acc11); EPI(1, 2, acc12); EPI(1, 3, acc13);
    EPI(2, 0, acc20); EPI(2, 1, acc21); EPI(2, 2, acc22); EPI(2, 3, acc23);
    EPI(3, 0, acc30); EPI(3, 1, acc31); EPI(3, 2, acc32); EPI(3, 3, acc33);
}

extern "C" void kernel_launch(void* const* d_in, const int* in_sizes, int n_in,
                              void* d_out, int out_size, void* d_ws, size_t ws_size,
                              hipStream_t stream) {
    const float* x     = (const float*)d_in[0];
    const float* gamma = (const float*)d_in[1];
    const float* beta  = (const float*)d_in[2];
    const float* rmean = (const float*)d_in[3];
    const float* rvar  = (const float*)d_in[4];
    const float* W     = (const float*)d_in[5];
    float* out = (float*)d_out;

    // ws layout: [bf16 W: 86016*2 B][ss2: 672 float2]  (~177 KB)
    unsigned short* Wbf = (unsigned short*)d_ws;
    float2* ss2 = (float2*)((char*)d_ws + (size_t)C_OUT * C_IN * 2);

    prep_kernel<<<(C_OUT * C_IN + 255) / 256, 256, 0, stream>>>(
        gamma, beta, rmean, rvar, W, Wbf, ss2);
    // 512 blocks x 256 thr: 2 b's per block (2 o-half waves each)
    gemm_kernel<<<512, 256, 0, stream>>>(x, Wbf, ss2, out);
}

// Round 10
// 225.455 us; speedup vs baseline: 1.0372x; 1.0372x over previous
//
#include <hip/hip_runtime.h>

#define C_IN   672
#define C_OUT  128
#define HW     49
#define XELEMS (C_IN*HW)      // 32928
#define BK     32             // K per step = one MFMA k-step
#define NK     21             // 672/32
#define CHUNK  (BK*HW)        // 1568

typedef short  short8 __attribute__((ext_vector_type(8)));
typedef float  f8v    __attribute__((ext_vector_type(8)));
typedef float  f4     __attribute__((ext_vector_type(4)));
typedef float  f2     __attribute__((ext_vector_type(2)));

typedef const __attribute__((address_space(1))) float*  gfp;
typedef const __attribute__((address_space(1))) f2*     gf2p;
typedef const __attribute__((address_space(1))) short8* gs8p;
typedef const __attribute__((address_space(1))) unsigned short* gusp;
typedef __attribute__((address_space(1))) float*        gwp;
typedef const __attribute__((address_space(3))) f4*     lf4p;

__device__ __forceinline__ void waitlgkm0() {
    asm volatile("s_waitcnt lgkmcnt(0)" ::: "memory");
}

__device__ __forceinline__ unsigned short f2bf(float f) {
    unsigned u = __float_as_uint(f);
    u += 0x7fffu + ((u >> 16) & 1u);
    return (unsigned short)(u >> 16);
}

__global__ __launch_bounds__(256) void prep_kernel(
        const float* __restrict__ gamma,
        const float* __restrict__ beta,
        const float* __restrict__ rmean,
        const float* __restrict__ rvar,
        const float* __restrict__ W,
        unsigned short* __restrict__ Wbf,
        float2* __restrict__ ss2) {
    int i = blockIdx.x * 256 + threadIdx.x;
    if (i < C_IN) {
        float inv = rsqrtf(rvar[i] + 1e-5f);
        float sc  = gamma[i] * inv;
        ss2[i] = make_float2(sc, beta[i] - rmean[i] * sc);
    }
    if (i < C_OUT * C_IN) Wbf[i] = f2bf(W[i]);
}

// out_b(128x49) = W(128x672) @ relu(x_b*scale+shift)(672x49), via operand
// swap (A = h^T from global, B = W^T, D = out^T fragments) -- see R14.
// R15 = R14 + SCHEDULING FENCE, one variable. R14's VGPR_Count=72 proved
// the compiler SANK every x/W load to its use point (only the 64 acc VGPRs
// were live): the E/O double-buffer existed in source only, each step
// issued 36 loads and immediately waited -> 80% dead time (MfmaUtil 5%,
// VALUBusy 13%), gemm 84us. Fix: asm volatile("" ::: "memory") immediately
// after each issue group. Loads cannot sink across a may-write-memory asm,
// and (unlike a "+v" operand pin) an operand-free fence forces NO waitcnt:
// the s_waitcnt still binds to the register USE a full step later. This is
// the minimal source construct that makes hipcc emit issue-early/wait-late.
// Verification signal: VGPR_Count must jump to ~180.
__global__ __launch_bounds__(256, 2) void gemm_kernel(
        const float* __restrict__ x,
        const unsigned short* __restrict__ Wbf,
        const float2* __restrict__ ss2,
        float* __restrict__ out) {
    __shared__ f2 s_ss[C_IN];            // (scale,shift) interleaved, 5.4 KB

    const int tid  = threadIdx.x;
    const int wv   = tid >> 6;           // 0..3
    const int lane = tid & 63;
    const int quad = lane >> 4;
    const int l16  = lane & 15;
    const int b     = blockIdx.x * 2 + (wv >> 1);
    const int obase = (wv & 1) * 64;     // o-half of this wave

    gfp  xg = (gfp)x;
    gusp wg = (gusp)Wbf;
    gwp  og = (gwp)out;
    lf4p ssl4 = (lf4p)&s_ss[0];

    // stage ss table (f2, coalesced); only barrier in the kernel.
    for (int i = tid; i < C_IN; i += 256)
        s_ss[i] = ((gf2p)ss2)[i];
    waitlgkm0();
    __builtin_amdgcn_s_barrier();

    const gfp xbp = xg + (size_t)b * XELEMS;

    // ---- named SSA state (ext-vectors, constant-indexed only) ----
    f8v xE0, xE1, xE2, xE3, xO0, xO1, xO2, xO3;   // x raw: 4 s-tiles x 8 c
    short8 wE0, wE1, wE2, wE3, wO0, wO1, wO2, wO3; // W^T frags: 4 o-tiles
    f4 acc00={0,0,0,0}, acc01={0,0,0,0}, acc02={0,0,0,0}, acc03={0,0,0,0};
    f4 acc10={0,0,0,0}, acc11={0,0,0,0}, acc12={0,0,0,0}, acc13={0,0,0,0};
    f4 acc20={0,0,0,0}, acc21={0,0,0,0}, acc22={0,0,0,0}, acc23={0,0,0,0};
    f4 acc30={0,0,0,0}, acc31={0,0,0,0}, acc32={0,0,0,0}, acc33={0,0,0,0};

// scheduling fence: loads above it may not sink below (may-write-memory
// asm); no operands -> no forced waitcnt. The load ISSUE stays here, the
// wait stays at the use one step later.
#define SFENCE asm volatile("" ::: "memory")

// 32 dword loads: tile t covers A rows s = t*16+l16 (tile 3 clamped to s=48;
// rows 49..63 feed only unstored D rows -- garbage OK). c = kc*32+quad*8+j.
// Per inst: 4 quads x 16 consecutive dwords = 4 full 64B lines.
#define ISSUE_X(S, kc) do {                                             \
    gfp _b = xbp + (size_t)(kc) * CHUNK + (size_t)quad * 8 * HW;        \
    _Pragma("unroll")                                                   \
    for (int j = 0; j < 8; ++j) {                                       \
        x##S##0[j] = _b[j * HW + l16];                                  \
        x##S##1[j] = _b[j * HW + 16 + l16];                             \
        x##S##2[j] = _b[j * HW + 32 + l16];                             \
        x##S##3[j] = _b[j * HW + 48];                                   \
    } } while (0)

// B = W^T frag: lane holds B[k=quad*8+j][n=l16], value = Wbf[o][c]:
// contiguous short8 at row o = obase + nt*16 + l16.
#define ISSUE_W(S, kc) do {                                             \
    gusp _w = wg + (size_t)(obase + l16) * C_IN + (kc) * BK + quad * 8; \
    w##S##0 = *(gs8p)(_w);                                              \
    w##S##1 = *(gs8p)(_w + 16 * C_IN);                                  \
    w##S##2 = *(gs8p)(_w + 32 * C_IN);                                  \
    w##S##3 = *(gs8p)(_w + 48 * C_IN);                                  \
} while (0)

#define BF1(xv, sc, sh) f2bf(fmaxf((xv) * (sc) + (sh), 0.f))
// build one A-frag from 8 raw x + 4 ss-f4s (each f4 = sc0,sh0,sc1,sh1)
#define MKA1(AF, XV, u0, u1, u2, u3) do {                               \
    AF[0] = (short)BF1(XV[0], u0[0], u0[1]);                            \
    AF[1] = (short)BF1(XV[1], u0[2], u0[3]);                            \
    AF[2] = (short)BF1(XV[2], u1[0], u1[1]);                            \
    AF[3] = (short)BF1(XV[3], u1[2], u1[3]);                            \
    AF[4] = (short)BF1(XV[4], u2[0], u2[1]);                            \
    AF[5] = (short)BF1(XV[5], u2[2], u2[3]);                            \
    AF[6] = (short)BF1(XV[6], u3[0], u3[1]);                            \
    AF[7] = (short)BF1(XV[7], u3[2], u3[3]);                            \
} while (0)

#define MM(ACC, AF, WF) ACC = __builtin_amdgcn_mfma_f32_16x16x32_bf16(AF, WF, ACC, 0, 0, 0)

// step K: issue K+1 (both streams) + FENCE -> ss broadcast read -> in-reg
// transform of K (counted vmcnt: K+1's 36 ops stay outstanding) -> 16 MFMAs.
#define STEP(K, C, N) do {                                              \
    if ((K) + 1 < NK) { ISSUE_X(N, (K) + 1); ISSUE_W(N, (K) + 1); SFENCE; } \
    int _sb = (K) * 16 + quad * 4;                                      \
    f4 u0 = ssl4[_sb], u1 = ssl4[_sb + 1], u2 = ssl4[_sb + 2], u3 = ssl4[_sb + 3]; \
    short8 af0, af1, af2, af3;                                          \
    MKA1(af0, x##C##0, u0, u1, u2, u3);                                 \
    MKA1(af1, x##C##1, u0, u1, u2, u3);                                 \
    MKA1(af2, x##C##2, u0, u1, u2, u3);                                 \
    MKA1(af3, x##C##3, u0, u1, u2, u3);                                 \
    MM(acc00, af0, w##C##0); MM(acc01, af0, w##C##1);                   \
    MM(acc02, af0, w##C##2); MM(acc03, af0, w##C##3);                   \
    MM(acc10, af1, w##C##0); MM(acc11, af1, w##C##1);                   \
    MM(acc12, af1, w##C##2); MM(acc13, af1, w##C##3);                   \
    MM(acc20, af2, w##C##0); MM(acc21, af2, w##C##1);                   \
    MM(acc22, af2, w##C##2); MM(acc23, af2, w##C##3);                   \
    MM(acc30, af3, w##C##0); MM(acc31, af3, w##C##1);                   \
    MM(acc32, af3, w##C##2); MM(acc33, af3, w##C##3);                   \
} while (0)

    ISSUE_X(E, 0); ISSUE_W(E, 0); SFENCE;
    STEP(0,  E, O); STEP(1,  O, E); STEP(2,  E, O); STEP(3,  O, E);
    STEP(4,  E, O); STEP(5,  O, E); STEP(6,  E, O); STEP(7,  O, E);
    STEP(8,  E, O); STEP(9,  O, E); STEP(10, E, O); STEP(11, O, E);
    STEP(12, E, O); STEP(13, O, E); STEP(14, E, O); STEP(15, O, E);
    STEP(16, E, O); STEP(17, O, E); STEP(18, E, O); STEP(19, O, E);
    STEP(20, E, O);

    // epilogue: D row = s = st*16 + quad*4 + i (contiguous i), col = o.
    // st<3 fully valid; st=3 only s=48 (quad 0, reg 0).
    gwp ob = og + (size_t)b * (C_OUT * HW);
#define EPI(ST, NT, ACC) do {                                           \
    int _o = obase + (NT) * 16 + l16;                                   \
    if ((ST) < 3) {                                                     \
        gwp _p = ob + (size_t)_o * HW + (ST) * 16 + quad * 4;           \
        _p[0] = ACC[0]; _p[1] = ACC[1]; _p[2] = ACC[2]; _p[3] = ACC[3]; \
    } else if (quad == 0) {                                             \
        ob[(size_t)_o * HW + 48] = ACC[0];                              \
    } } while (0)
    EPI(0, 0, acc00); EPI(0, 1, acc01); EPI(0, 2, acc02); EPI(0, 3, acc03);
    EPI(1, 0, acc10); EPI(1, 1, acc11); EPI(1, 2, acc12); EPI(1, 3, acc13);
    EPI(2, 0, acc20); EPI(2, 1, acc21); EPI(2, 2, acc22); EPI(2, 3, acc23);
    EPI(3, 0, acc30); EPI(3, 1, acc31); EPI(3, 2, acc32); EPI(3, 3, acc33);
}

extern "C" void kernel_launch(void* const* d_in, const int* in_sizes, int n_in,
                              void* d_out, int out_size, void* d_ws, size_t ws_size,
                              hipStream_t stream) {
    const float* x     = (const float*)d_in[0];
    const float* gamma = (const float*)d_in[1];
    const float* beta  = (const float*)d_in[2];
    const float* rmean = (const float*)d_in[3];
    const float* rvar  = (const float*)d_in[4];
    const float* W     = (const float*)d_in[5];
    float* out = (float*)d_out;

    // ws layout: [bf16 W: 86016*2 B][ss2: 672 float2]  (~177 KB)
    unsigned short* Wbf = (unsigned short*)d_ws;
    float2* ss2 = (float2*)((char*)d_ws + (size_t)C_OUT * C_IN * 2);

    prep_kernel<<<(C_OUT * C_IN + 255) / 256, 256, 0, stream>>>(
        gamma, beta, rmean, rvar, W, Wbf, ss2);
    // 512 blocks x 256 thr: 2 b's per block (2 o-half waves each)
    gemm_kernel<<<512, 256, 0, stream>>>(x, Wbf, ss2, out);
}